// Round 2
// baseline (962.856 us; speedup 1.0000x reference)
//
#include <hip/hip_runtime.h>
#include <math.h>

#define K_DIM 4096
#define N_DIM 256
#define M_DIM 16384
#define NSTAGES 128        // K / 32

typedef short bf8v __attribute__((ext_vector_type(8)));
typedef float f32x16 __attribute__((ext_vector_type(16)));
typedef unsigned short us8 __attribute__((ext_vector_type(8)));

union AB { unsigned u[4]; bf8v v; };

// RNE pack of two f32 -> two bf16 (lo half = src0). gfx950 HW instr; no builtin.
__device__ __forceinline__ unsigned cvt_pk(float a, float b) {
    unsigned r;
    asm("v_cvt_pk_bf16_f32 %0, %1, %2" : "=v"(r) : "v"(a), "v"(b));
    return r;
}

// ---------------- W pretile into per-lane MFMA fragment order --------------
// Bt granule (16 B = 8 bf16): index [s][w(8)][h(2: hi/lo)][ks(2)][lane(64)]
// granule(s,w,h,ks,l)[j] = split_h( W[s*32 + ks*16 + (l>>5)*8 + j][w*32 + (l&31)] )
// Extra block (blockIdx.x == NSTAGES) computes beta:
//   beta[j] = bias[j] + (1/4096) * prod_{d,k} cos^2(uw[d, j, k])
__global__ void pretile_w_kernel(const float* __restrict__ W,
                                 unsigned short* __restrict__ Bt,
                                 const float* __restrict__ uw,
                                 const float* __restrict__ bias,
                                 float* __restrict__ beta) {
    const int t = threadIdx.x;
    if (blockIdx.x == NSTAGES) {   // beta block
        float p = 1.0f / 4096.0f;
        #pragma unroll
        for (int d = 0; d < 9; ++d) {
            const float* a = uw + (size_t)d * (K_DIM * N_DIM) + (size_t)t * N_DIM;
            #pragma unroll
            for (int k = 0; k < 3; ++k) {
                float c = cosf(a[k]);
                p *= c * c;
            }
        }
        beta[t] = bias[t] + p;
        return;
    }
    const int s = blockIdx.x;     // 0..127
    #pragma unroll
    for (int g = 0; g < 8; ++g) {
        const int G  = g * 256 + t;       // 0..2047
        const int w  = G >> 8;
        const int h  = (G >> 7) & 1;
        const int ks = (G >> 6) & 1;
        const int l  = G & 63;
        const int n  = w * 32 + (l & 31);
        const int k0 = s * 32 + ks * 16 + (l >> 5) * 8;
        unsigned short o8[8];
        #pragma unroll
        for (int j = 0; j < 8; ++j) {
            float f = W[(size_t)(k0 + j) * N_DIM + n];
            unsigned u = __float_as_uint(f);
            unsigned hh = u + 0x7fffu + ((u >> 16) & 1u);     // RNE bf16 hi
            if (h == 0) {
                o8[j] = (unsigned short)(hh >> 16);
            } else {
                float r = f - __uint_as_float(hh & 0xffff0000u);  // exact residual
                unsigned ur = __float_as_uint(r);
                o8[j] = (unsigned short)((ur + 0x7fffu + ((ur >> 16) & 1u)) >> 16);
            }
        }
        *(us8*)&Bt[((size_t)s * 2048 + G) * 8] = *(us8*)&o8[0];
    }
}

// ---------------- GEMM + tanh: barrier-free streaming ----------------
// out[m,n] = tanh(sum_k x[m,k]*W[k,n] + beta[n]); 3-term bf16 split.
// Block = 256 thr = 4 waves; wave-tile 32m x 32n, waves partitioned along M:
// wave w owns PRIVATE rows [by*128 + w*32, +32), n-strip = bx*32 (same for all
// waves in block -> B frags identical across waves -> L1 broadcast).
// mfma_f32_32x32x16_bf16: A row=l&31, k=(l>>5)*8+j (harness-verified r1);
// D col=l&31, row=(r&3)+8*(r>>2)+4*(l>>5) [m74/m101, verified r0/r1].
// A: direct global->VGPR fp32 (lane reads its own row; lh0/lh1 x ks0/ks1 tile
//    the 128-B stage window -> full line utilization), cvt_pk to hi/lo in reg.
// NO LDS, NO barriers, NO asm waits. Prefetch depth 2 on A and B; all loads
// compiler-tracked. 1024 blocks, no LDS, ~110 VGPR -> 4 blocks/CU, all resident.
__global__ __launch_bounds__(256, 4)
void gemm_tanh_kernel(const float* __restrict__ X,
                      const unsigned short* __restrict__ Bt,
                      const float* __restrict__ beta,
                      float* __restrict__ out) {
    const int t = threadIdx.x;
    const int lane = t & 63;
    const int w = t >> 6;            // wave id = m-strip within block
    const int l31 = lane & 31;
    const int lh = lane >> 5;
    const int bn = blockIdx.x;       // n-strip 0..7
    const int mrow = blockIdx.y * 128 + w * 32 + l31;   // this lane's A row

    // A: lane's fragment floats for stage s, ks: X[mrow][s*32 + ks*16 + lh*8 + j]
    const float* pa = X + (size_t)mrow * K_DIM + lh * 8;
    // B: pretiled frags; shorts offset = s*16384 + bn*2048 + h*1024 + ks*512 + l*8
    const unsigned short* pb = Bt + bn * 2048 + lane * 8;

    f32x16 acc = (f32x16)(0.0f);
    float4 a0_0, a0_1, a0_2, a0_3;   // raw A, stage parity 0 (ks0: 0,1; ks1: 2,3)
    float4 a1_0, a1_1, a1_2, a1_3;   // raw A, stage parity 1
    AB b0_0, b0_1, b0_2, b0_3;       // B frags parity 0: hi ks0, hi ks1, lo ks0, lo ks1
    AB b1_0, b1_1, b1_2, b1_3;

#define LOADA(P, sidx) { \
    const float* p_ = pa + (size_t)(sidx) * 32; \
    a##P##_0 = *(const float4*)(p_);      \
    a##P##_1 = *(const float4*)(p_ + 4);  \
    a##P##_2 = *(const float4*)(p_ + 16); \
    a##P##_3 = *(const float4*)(p_ + 20); }

#define LOADB(P, sidx) { \
    const unsigned short* p_ = pb + (size_t)(sidx) * 16384; \
    b##P##_0.v = *(const bf8v*)(p_);        \
    b##P##_1.v = *(const bf8v*)(p_ + 512);  \
    b##P##_2.v = *(const bf8v*)(p_ + 1024); \
    b##P##_3.v = *(const bf8v*)(p_ + 1536); }

#define CVT8(f0, f1, hi, lo) { \
    float x0_ = f0.x, x1_ = f0.y, x2_ = f0.z, x3_ = f0.w; \
    float x4_ = f1.x, x5_ = f1.y, x6_ = f1.z, x7_ = f1.w; \
    unsigned h0_ = cvt_pk(x0_, x1_); \
    unsigned h1_ = cvt_pk(x2_, x3_); \
    unsigned h2_ = cvt_pk(x4_, x5_); \
    unsigned h3_ = cvt_pk(x6_, x7_); \
    hi.u[0] = h0_; hi.u[1] = h1_; hi.u[2] = h2_; hi.u[3] = h3_; \
    lo.u[0] = cvt_pk(x0_ - __uint_as_float(h0_ << 16), x1_ - __uint_as_float(h0_ & 0xffff0000u)); \
    lo.u[1] = cvt_pk(x2_ - __uint_as_float(h1_ << 16), x3_ - __uint_as_float(h1_ & 0xffff0000u)); \
    lo.u[2] = cvt_pk(x4_ - __uint_as_float(h2_ << 16), x5_ - __uint_as_float(h2_ & 0xffff0000u)); \
    lo.u[3] = cvt_pk(x6_ - __uint_as_float(h3_ << 16), x7_ - __uint_as_float(h3_ & 0xffff0000u)); }

#define MFMA(a, b) acc = __builtin_amdgcn_mfma_f32_32x32x16_bf16((a), (b), acc, 0, 0, 0)

    // Body: convert A(s) (loaded 2 stages ago), reissue A(s+2) into same regs;
    // 6 MFMA with B(s) (loaded 2 stages ago), reissue B(s+2). No sync anywhere.
#define BODY(P, s) { \
    AB ah0_, al0_, ah1_, al1_; \
    CVT8(a##P##_0, a##P##_1, ah0_, al0_); \
    CVT8(a##P##_2, a##P##_3, ah1_, al1_); \
    LOADA(P, ((s) + 2) & 127); \
    MFMA(ah0_.v, b##P##_0.v); \
    MFMA(al0_.v, b##P##_0.v); \
    MFMA(ah0_.v, b##P##_2.v); \
    MFMA(ah1_.v, b##P##_1.v); \
    MFMA(al1_.v, b##P##_1.v); \
    MFMA(ah1_.v, b##P##_3.v); \
    LOADB(P, ((s) + 2) & 127); \
}

    // Prologue: depth-2 prefetch.
    LOADA(0, 0); LOADA(1, 1);
    LOADB(0, 0); LOADB(1, 1);

    for (int s = 0; s < NSTAGES; s += 2) {
        BODY(0, s);
        BODY(1, s + 1);
    }

#undef BODY
#undef MFMA
#undef CVT8
#undef LOADB
#undef LOADA

    // Epilogue: D col = l&31 (n), row = (r&3) + 8*(r>>2) + 4*lh (m).
    const float bet = beta[bn * 32 + l31];
    float* po = out + (size_t)(blockIdx.y * 128 + w * 32 + 4 * lh) * N_DIM + bn * 32 + l31;
    #pragma unroll
    for (int r = 0; r < 16; ++r) {
        const int row = (r & 3) + 8 * (r >> 2);
        po[(size_t)row * N_DIM] = tanhf(acc[r] + bet);
    }
}

extern "C" void kernel_launch(void* const* d_in, const int* in_sizes, int n_in,
                              void* d_out, int out_size, void* d_ws, size_t ws_size,
                              hipStream_t stream) {
    const float* x    = (const float*)d_in[0];
    const float* uw   = (const float*)d_in[1];
    const float* W    = (const float*)d_in[2];
    const float* bias = (const float*)d_in[3];
    float* out = (float*)d_out;

    // workspace: Bt pretiled (4 MB) | beta (1 KB)
    char* ws = (char*)d_ws;
    unsigned short* bt = (unsigned short*)ws;
    float* beta = (float*)(ws + (size_t)4 * 1024 * 1024);

    pretile_w_kernel<<<dim3(NSTAGES + 1), 256, 0, stream>>>(W, bt, uw, bias, beta);

    gemm_tanh_kernel<<<dim3(N_DIM / 32, M_DIM / 128), 256, 0, stream>>>(x, bt, beta, out);
}

// Round 3
// 575.537 us; speedup vs baseline: 1.6730x; 1.6730x over previous
//
#include <hip/hip_runtime.h>
#include <math.h>

#define K_DIM 4096
#define N_DIM 256
#define M_DIM 16384
#define NSTAGES 128      // K / 32 (global stages)
#define NSTW 64          // stages per wave (K/2, 32 k each)

typedef short bf8v __attribute__((ext_vector_type(8)));
typedef float f32x16 __attribute__((ext_vector_type(16)));
typedef unsigned short us8 __attribute__((ext_vector_type(8)));

union AB { unsigned u[4]; bf8v v; };

// RNE pack of two f32 -> two bf16 (lo half = src0). gfx950 HW instr; no builtin.
__device__ __forceinline__ unsigned cvt_pk(float a, float b) {
    unsigned r;
    asm("v_cvt_pk_bf16_f32 %0, %1, %2" : "=v"(r) : "v"(a), "v"(b));
    return r;
}

// ---------------- W pretile into per-lane MFMA fragment order --------------
// (verified r1/r2) Bt granule (16 B = 8 bf16): [s][strip(8)][h(2)][ks(2)][lane(64)]
// granule(s,strip,h,ks,l)[j] = split_h( W[s*32 + ks*16 + (l>>5)*8 + j][strip*32 + (l&31)] )
// Extra block (blockIdx.x == NSTAGES) computes beta:
//   beta[j] = bias[j] + (1/4096) * prod_{d,k} cos^2(uw[d, j, k])
__global__ void pretile_w_kernel(const float* __restrict__ W,
                                 unsigned short* __restrict__ Bt,
                                 const float* __restrict__ uw,
                                 const float* __restrict__ bias,
                                 float* __restrict__ beta) {
    const int t = threadIdx.x;
    if (blockIdx.x == NSTAGES) {   // beta block
        float p = 1.0f / 4096.0f;
        #pragma unroll
        for (int d = 0; d < 9; ++d) {
            const float* a = uw + (size_t)d * (K_DIM * N_DIM) + (size_t)t * N_DIM;
            #pragma unroll
            for (int k = 0; k < 3; ++k) {
                float c = cosf(a[k]);
                p *= c * c;
            }
        }
        beta[t] = bias[t] + p;
        return;
    }
    const int s = blockIdx.x;     // 0..127
    #pragma unroll
    for (int g = 0; g < 8; ++g) {
        const int G  = g * 256 + t;       // 0..2047
        const int w  = G >> 8;
        const int h  = (G >> 7) & 1;
        const int ks = (G >> 6) & 1;
        const int l  = G & 63;
        const int n  = w * 32 + (l & 31);
        const int k0 = s * 32 + ks * 16 + (l >> 5) * 8;
        unsigned short o8[8];
        #pragma unroll
        for (int j = 0; j < 8; ++j) {
            float f = W[(size_t)(k0 + j) * N_DIM + n];
            unsigned u = __float_as_uint(f);
            unsigned hh = u + 0x7fffu + ((u >> 16) & 1u);     // RNE bf16 hi
            if (h == 0) {
                o8[j] = (unsigned short)(hh >> 16);
            } else {
                float r = f - __uint_as_float(hh & 0xffff0000u);  // exact residual
                unsigned ur = __float_as_uint(r);
                o8[j] = (unsigned short)((ur + 0x7fffu + ((ur >> 16) & 1u)) >> 16);
            }
        }
        *(us8*)&Bt[((size_t)s * 2048 + G) * 8] = *(us8*)&o8[0];
    }
}

// ---------------- GEMM + tanh ----------------
// Block = 32 rows x 256 cols, 4 waves = {kh: K-half} x {nh: N-half}.
// Wave: 32 rows x 128 cols x K/2, 64 stages of 32k, mfma_f32_32x32x16_bf16,
// acc = 4 n-tiles x 16. Zero barriers in main loop (wave-private pipeline):
//  A: coalesced chunk loads (8 rows x 128-B lines/instr) -> cvt_pk hi/lo once
//     per element -> wave-private XOR-swizzled LDS (2 x 4 KB), lgkmcnt-only.
//     nh-peers re-read same slice (L1 hit); kh disjoint -> X from HBM once.
//  B: reg frags from pretiled Bt (own 128-col slice only), half-stage prefetch.
// Epilogue: kh=1 waves dump acc to LDS, one __syncthreads, kh=0 adds + tanh.
// Frag maps (verified r2): A row=l&31, k=ks*16+(l>>5)*8+j; B col=l&31 same k;
// D col=l&31, row=(r&3)+8*(r>>2)+4*(l>>5).
__global__ __launch_bounds__(256, 2)
void gemm_tanh_kernel(const float* __restrict__ X,
                      const unsigned short* __restrict__ Bt,
                      const float* __restrict__ beta,
                      float* __restrict__ out) {
    __shared__ __align__(16) char alds[4][2][4096];   // [wave][buf][32 rows x 128 B]
    __shared__ __align__(16) float eps[2][4][64][16]; // [nh][nt][lane][r] 32 KB

    const int t = threadIdx.x;
    const int lane = t & 63;
    const int w = t >> 6;
    const int kh = w & 1;
    const int nh = w >> 1;
    const int l31 = lane & 31;
    const int lh = lane >> 5;
    const int m0 = blockIdx.x * 32;

    char* wb = &alds[w][0][0];

    // ---- A raw staging: chunk (row cr+8i, part cp): fully coalesced lines ----
    const int cr = lane >> 3;          // 0..7
    const int cp = lane & 7;           // 16-B part of the 128-B stage window
    const float* pa = X + (size_t)(m0 + cr) * K_DIM + kh * (K_DIM / 2) + cp * 4;

    // LDS write offsets (octet o = cp>>1 swizzled by row&7; same for all i since i*8 keeps row&7)
    const int swz = cr & 7;
    const int wo_h = cr * 128 + ((((cp >> 1)    ) ^ swz) << 4) + (cp & 1) * 8;
    const int wo_l = cr * 128 + ((((cp >> 1) | 4) ^ swz) << 4) + (cp & 1) * 8;

    // Frag read offsets: octet o = ks*2+lh (hi), |4 (lo), swizzled by row&7
    const int fs = l31 & 7;
    const int ro_h0 = l31 * 128 + (((0 + lh)      ^ fs) << 4);
    const int ro_h1 = l31 * 128 + (((2 + lh)      ^ fs) << 4);
    const int ro_l0 = l31 * 128 + ((((0 + lh) | 4) ^ fs) << 4);
    const int ro_l1 = l31 * 128 + ((((2 + lh) | 4) ^ fs) << 4);

    // B: shorts offset = abs_s*16384 + strip*2048 + h*1024 + ks*512 + lane*8
    const unsigned short* pb = Bt + (size_t)(kh * NSTW) * 16384
                                  + (size_t)(nh * 4) * 2048 + lane * 8;

    f32x16 acc[4];
    #pragma unroll
    for (int nt = 0; nt < 4; ++nt) acc[nt] = (f32x16)(0.0f);

    float4 raA[4], raB[4];
    AB bs0[8], bs1[8];   // [nt*2 + h] for ks0 / ks1

#define LOADA(dst, sidx) { \
    const float* p_ = pa + (size_t)(sidx) * 32; \
    _Pragma("unroll") for (int i_ = 0; i_ < 4; ++i_) \
        dst[i_] = *(const float4*)(p_ + (size_t)i_ * 8 * K_DIM); }

#define CVTWR(src, boff) { \
    _Pragma("unroll") for (int i_ = 0; i_ < 4; ++i_) { \
        float4 f_ = src[i_]; \
        unsigned h0_ = cvt_pk(f_.x, f_.y); \
        unsigned h1_ = cvt_pk(f_.z, f_.w); \
        float r0_ = f_.x - __uint_as_float(h0_ << 16); \
        float r1_ = f_.y - __uint_as_float(h0_ & 0xffff0000u); \
        float r2_ = f_.z - __uint_as_float(h1_ << 16); \
        float r3_ = f_.w - __uint_as_float(h1_ & 0xffff0000u); \
        unsigned l0_ = cvt_pk(r0_, r1_); \
        unsigned l1_ = cvt_pk(r2_, r3_); \
        *(uint2*)(wb + (boff) + i_ * 1024 + wo_h) = make_uint2(h0_, h1_); \
        *(uint2*)(wb + (boff) + i_ * 1024 + wo_l) = make_uint2(l0_, l1_); } }

#define LOADB(set, sidx, ks) { \
    const unsigned short* p_ = pb + (size_t)(sidx) * 16384 + (ks) * 512; \
    _Pragma("unroll") for (int nt_ = 0; nt_ < 4; ++nt_) { \
        set[nt_ * 2 + 0].v = *(const bf8v*)(p_ + nt_ * 2048); \
        set[nt_ * 2 + 1].v = *(const bf8v*)(p_ + nt_ * 2048 + 1024); } }

#define MFMA3(ah, al, set) { \
    _Pragma("unroll") for (int nt_ = 0; nt_ < 4; ++nt_) { \
        acc[nt_] = __builtin_amdgcn_mfma_f32_32x32x16_bf16((ah).v, set[nt_*2].v,   acc[nt_], 0,0,0); \
        acc[nt_] = __builtin_amdgcn_mfma_f32_32x32x16_bf16((al).v, set[nt_*2].v,   acc[nt_], 0,0,0); \
        acc[nt_] = __builtin_amdgcn_mfma_f32_32x32x16_bf16((ah).v, set[nt_*2+1].v, acc[nt_], 0,0,0); } }

// One stage: read frags(s) from CB, cvt+write data(s+1) to NB, reload RA with
// raw(s+3), compute ks0 / ks1 with bs0/bs1, reissue each B set for stage s+1.
#define PHASE(s, CB, NB, RA) { \
    AB ah0_, al0_, ah1_, al1_; \
    ah0_.v = *(const bf8v*)(wb + (CB) + ro_h0); \
    al0_.v = *(const bf8v*)(wb + (CB) + ro_l0); \
    ah1_.v = *(const bf8v*)(wb + (CB) + ro_h1); \
    al1_.v = *(const bf8v*)(wb + (CB) + ro_l1); \
    CVTWR(RA, NB); \
    { int sx_ = (s) + 3; if (sx_ > 63) sx_ = 63; LOADA(RA, sx_); } \
    MFMA3(ah0_, al0_, bs0); \
    LOADB(bs0, ((s) + 1) & 63, 0); \
    MFMA3(ah1_, al1_, bs1); \
    LOADB(bs1, ((s) + 1) & 63, 1); }

    // Prologue: stage 0 into buf0; raw depth 2; B depth 1 stage.
    {
        float4 tmp[4];
        LOADA(tmp, 0);
        CVTWR(tmp, 0);
    }
    LOADA(raA, 1);
    LOADA(raB, 2);
    LOADB(bs0, 0, 0);
    LOADB(bs1, 0, 1);

    for (int s = 0; s < NSTW; s += 2) {
        PHASE(s,     0,    4096, raA);
        PHASE(s + 1, 4096, 0,    raB);
    }

#undef PHASE
#undef MFMA3
#undef LOADB
#undef CVTWR
#undef LOADA

    // ---- epilogue: combine K-halves, + beta, tanh, store ----
    if (kh == 1) {
        #pragma unroll
        for (int nt = 0; nt < 4; ++nt)
            #pragma unroll
            for (int q = 0; q < 4; ++q)
                *(float4*)&eps[nh][nt][lane][q * 4] =
                    make_float4(acc[nt][q * 4], acc[nt][q * 4 + 1],
                                acc[nt][q * 4 + 2], acc[nt][q * 4 + 3]);
    }
    __syncthreads();
    if (kh == 0) {
        #pragma unroll
        for (int nt = 0; nt < 4; ++nt) {
            const int col = nh * 128 + nt * 32 + l31;
            const float bet = beta[col];
            float* po = out + (size_t)(m0 + 4 * lh) * N_DIM + col;
            #pragma unroll
            for (int r = 0; r < 16; ++r) {
                const int row = (r & 3) + 8 * (r >> 2);
                float v = acc[nt][r] + eps[nh][nt][lane][r] + bet;
                po[(size_t)row * N_DIM] = tanhf(v);
            }
        }
    }
}

extern "C" void kernel_launch(void* const* d_in, const int* in_sizes, int n_in,
                              void* d_out, int out_size, void* d_ws, size_t ws_size,
                              hipStream_t stream) {
    const float* x    = (const float*)d_in[0];
    const float* uw   = (const float*)d_in[1];
    const float* W    = (const float*)d_in[2];
    const float* bias = (const float*)d_in[3];
    float* out = (float*)d_out;

    // workspace: Bt pretiled (4 MB) | beta (1 KB)
    char* ws = (char*)d_ws;
    unsigned short* bt = (unsigned short*)ws;
    float* beta = (float*)(ws + (size_t)4 * 1024 * 1024);

    pretile_w_kernel<<<dim3(NSTAGES + 1), 256, 0, stream>>>(W, bt, uw, bias, beta);

    gemm_tanh_kernel<<<dim3(M_DIM / 32), 256, 0, stream>>>(x, bt, beta, out);
}